// Round 17
// baseline (412.634 us; speedup 1.0000x reference)
//
#include <hip/hip_runtime.h>
#include <hip/hip_bf16.h>

#define NNODES 50000
#define NEDGES 800000
#define UNITS 64
#define NTILES (NNODES/16)         // 3125 exact
#define NB_SCAN ((NNODES+255)/256) // 196
#define NB_NODE ((NTILES+3)/4)     // 782
#define NB_HIST ((NEDGES+255)/256) // 3125
#define NB_EDGE (NEDGES/256)       // 3125 exact
#define NB_POOL (NEDGES/16/4)      // 12500 exact (16-edge chunks, 4 waves/block)

typedef unsigned short ushort;
typedef unsigned int uint;
typedef __attribute__((ext_vector_type(8))) short bf16x8;
typedef __attribute__((ext_vector_type(4))) float floatx4;
typedef __attribute__((ext_vector_type(8))) ushort ushort8_t;

__device__ __forceinline__ ushort f2bf(float x){
  union{float f; uint u;} v; v.f = x;
  uint r = v.u + 0x7fffu + ((v.u >> 16) & 1u);   // RNE
  return (ushort)(r >> 16);
}
__device__ __forceinline__ float bf2f(ushort h){
  union{uint u; float f;} v; v.u = ((uint)h) << 16; return v.f;
}
__device__ __forceinline__ void split8(const float* __restrict__ p, bf16x8& hi, bf16x8& lo){
  #pragma unroll
  for (int j=0;j<8;++j){
    float x = p[j];
    ushort h = f2bf(x);
    hi[j] = (short)h;
    lo[j] = (short)f2bf(x - bf2f(h));
  }
}

// DPP butterfly add (VALU pipe, no LDS): xor1, xor2, xor7, xor15 basis -> 16-lane sum
template<int CTRL>
__device__ __forceinline__ float dpp_add(float x){
  int y = __builtin_amdgcn_update_dpp(0, __float_as_int(x), CTRL, 0xF, 0xF, true);
  return x + __int_as_float(y);
}
template<int CH>
__device__ __forceinline__ float lane_sum(float p){
  p = dpp_add<0xB1>(p);    // quad_perm xor1
  p = dpp_add<0x4E>(p);    // quad_perm xor2
  p = dpp_add<0x141>(p);   // row_half_mirror = xor7
  p = dpp_add<0x140>(p);   // row_mirror = xor15
  if (CH == 64){
    p += __shfl_xor(p, 16);
    p += __shfl_xor(p, 32);
  }
  return p;
}

// -------- weight pre-split unit (MFMA B-fragment order, bf16 hi/lo) --------

__device__ __forceinline__ void packunit(const float* __restrict__ W, int r8, int col,
                                         ushort* __restrict__ H, ushort* __restrict__ L){
  bf16x8 hi, lo;
  #pragma unroll
  for (int j=0;j<8;++j){
    float x = W[(r8*8+j)*64 + col];
    ushort h = f2bf(x);
    hi[j] = (short)h;
    lo[j] = (short)f2bf(x - bf2f(h));
  }
  *(bf16x8*)(H + ((size_t)r8*64 + col)*8) = hi;
  *(bf16x8*)(L + ((size_t)r8*64 + col)*8) = lo;
}

// -------- fused: hist+rank (blocks 0..NB_HIST) + splitw (rest) --------

__global__ void k_init(const int* __restrict__ recv, int* __restrict__ counts,
                       int* __restrict__ rank,
                       const float* __restrict__ Wq1, const float* __restrict__ Ws1,
                       const float* __restrict__ Wn1, const float* __restrict__ Wq2,
                       const float* __restrict__ Ws2, const float* __restrict__ Wn2,
                       const float* __restrict__ We1, const float* __restrict__ We2,
                       ushort* __restrict__ wsp){
  if (blockIdx.x < NB_HIST){
    int e = blockIdx.x*blockDim.x + threadIdx.x;
    if (e < NEDGES) rank[e] = atomicAdd(&counts[recv[e]], 1);
    return;
  }
  int u = (blockIdx.x - NB_HIST)*blockDim.x + threadIdx.x;   // 4608 units
  if (u >= 4608) return;
  ushort* p = wsp;
  const float* W; int base;
  if      (u < 512){  W=Wq1; base=u;        p += 0;      packunit(W, base>>6, base&63, p, p+4096); return; }
  else if (u < 1024){ W=Ws1; base=u-512;    p += 8192;   packunit(W, base>>6, base&63, p, p+4096); return; }
  else if (u < 2048){ W=Wn1; base=u-1024;   p += 16384;  packunit(W, base>>6, base&63, p, p+8192); return; }
  else if (u < 2560){ W=Wq2; base=u-2048;   p += 32768;  packunit(W, base>>6, base&63, p, p+4096); return; }
  else if (u < 3072){ W=Ws2; base=u-2560;   p += 40960;  packunit(W, base>>6, base&63, p, p+4096); return; }
  else if (u < 4096){ W=Wn2; base=u-3072;   p += 49152;  packunit(W, base>>6, base&63, p, p+8192); return; }
  else if (u < 4352){ W=We1; base=u-4096;   p += 65536;  packunit(W, base>>6, base&63, p, p+2048); return; }
  else {              W=We2; base=u-4352;   p += 69632;  packunit(W, base>>6, base&63, p, p+2048); return; }
}

// ---------------- scan: blocksum + fused(top-scan + final) ----------------

__global__ void k_blocksum(const int* __restrict__ counts, int* __restrict__ bsum){
  __shared__ int red[256];
  int b = blockIdx.x, t = threadIdx.x;
  int i = b*256 + t;
  red[t] = (i < NNODES) ? counts[i] : 0;
  __syncthreads();
  for (int s=128; s>0; s>>=1){ if (t<s) red[t]+=red[t+s]; __syncthreads(); }
  if (t==0) bsum[b] = red[0];
}

// each block redundantly reduces bsum[0..b) (196 L2-hot ints) for its prefix
__global__ void k_scanfinal(const int* __restrict__ counts, const int* __restrict__ bsum,
                            int* __restrict__ offsets){
  __shared__ int red[256];
  int b = blockIdx.x, t = threadIdx.x;
  red[t] = (t < b) ? bsum[t] : 0;                 // NB_SCAN <= 256
  __syncthreads();
  for (int s=128; s>0; s>>=1){ if (t<s) red[t]+=red[t+s]; __syncthreads(); }
  int pre = red[0];                               // exclusive block prefix
  __syncthreads();
  int i = b*256 + t;
  int own = (i < NNODES) ? counts[i] : 0;
  red[t] = own;
  __syncthreads();
  for (int s=1; s<256; s<<=1){
    int u = (t>=s) ? red[t-s] : 0;
    __syncthreads();
    red[t] += u;
    __syncthreads();
  }
  if (i < NNODES) offsets[i] = pre + red[t] - own;
  if (b == 0 && t == 0) offsets[NNODES] = NEDGES;
}

// -------- node transform tile: Q = h@Wq (fp32), Sb = h@Ws (bf16) --------

__device__ __forceinline__ void qs_tile(const float* __restrict__ h,
                                        const ushort* __restrict__ WqH, const ushort* __restrict__ WqL,
                                        const ushort* __restrict__ WsH, const ushort* __restrict__ WsL,
                                        float* __restrict__ Q, ushort* __restrict__ Sb,
                                        int tile, int tid){
  int lane = tid & 63;
  int m = lane & 15, quad = lane >> 4;
  size_t base = (size_t)tile*16;
  floatx4 accQ[4], accS[4];
  #pragma unroll
  for (int t=0;t<4;++t){ accQ[t]=(floatx4){0,0,0,0}; accS[t]=(floatx4){0,0,0,0}; }
  #pragma unroll
  for (int ks=0; ks<2; ++ks){
    bf16x8 ah, al;
    split8(h + (base+m)*64 + ks*32 + quad*8, ah, al);
    int r8 = ks*4 + quad;
    #pragma unroll
    for (int t4=0;t4<4;++t4){
      size_t fo = ((size_t)r8*64 + t4*16 + m)*8;
      const bf16x8 bh = *(const bf16x8*)(WqH + fo);
      const bf16x8 bl = *(const bf16x8*)(WqL + fo);
      const bf16x8 ch = *(const bf16x8*)(WsH + fo);
      const bf16x8 cl = *(const bf16x8*)(WsL + fo);
      accQ[t4] = __builtin_amdgcn_mfma_f32_16x16x32_bf16(al, bh, accQ[t4],0,0,0);
      accQ[t4] = __builtin_amdgcn_mfma_f32_16x16x32_bf16(ah, bl, accQ[t4],0,0,0);
      accQ[t4] = __builtin_amdgcn_mfma_f32_16x16x32_bf16(ah, bh, accQ[t4],0,0,0);
      accS[t4] = __builtin_amdgcn_mfma_f32_16x16x32_bf16(al, ch, accS[t4],0,0,0);
      accS[t4] = __builtin_amdgcn_mfma_f32_16x16x32_bf16(ah, cl, accS[t4],0,0,0);
      accS[t4] = __builtin_amdgcn_mfma_f32_16x16x32_bf16(ah, ch, accS[t4],0,0,0);
    }
  }
  #pragma unroll
  for (int t4=0;t4<4;++t4)
    #pragma unroll
    for (int r=0;r<4;++r){
      size_t row = base + quad*4 + r;
      Q[row*64 + t4*16 + m]  = accQ[t4][r];
      Sb[row*64 + t4*16 + m] = f2bf(accS[t4][r]);
    }
}

// -------- fused scatter+permute + layer-1 QS: ONE dispatch, NO atomics --------
// Edge blocks at the random-access BW floor (~2.2 TB/s, r14) -- structural.

__global__ void k_scatperm(const int* __restrict__ recv, const int* __restrict__ send,
                           const int* __restrict__ rank,
                           const float* __restrict__ ef,
                           ushort* __restrict__ efh, int* __restrict__ ssend,
                           const int* __restrict__ offsets, int* __restrict__ srecv,
                           float* __restrict__ num, float* __restrict__ den,
                           const float* __restrict__ h,
                           const ushort* __restrict__ WqH, const ushort* __restrict__ WqL,
                           const ushort* __restrict__ WsH, const ushort* __restrict__ WsL,
                           float* __restrict__ Q, ushort* __restrict__ Sb){
  if (blockIdx.x >= NB_EDGE + NB_SCAN){
    int tile = (int)(blockIdx.x - NB_EDGE - NB_SCAN)*4 + (threadIdx.x>>6);
    if (tile < NTILES) qs_tile(h, WqH, WqL, WsH, WsL, Q, Sb, tile, threadIdx.x);
    return;
  }
  if (blockIdx.x >= NB_EDGE){
    int n = (blockIdx.x - NB_EDGE)*256 + threadIdx.x;
    if (n < NNODES){
      int b = offsets[n], e = offsets[n+1];
      for (int j=b; j<e; ++j) srecv[j] = n;
      floatx4 z = {0.f,0.f,0.f,0.f};
      floatx4* pn = (floatx4*)(num + (size_t)n*64);
      #pragma unroll
      for (int j=0;j<16;++j) pn[j] = z;
      *(floatx4*)(den + (size_t)n*4) = z;
    }
    return;
  }
  int e = blockIdx.x*256 + threadIdx.x;            // NEDGES = 256*3125 exact
  int r = recv[e];
  int sv = send[e];
  int pos = offsets[r] + rank[e];
  ssend[pos] = sv;
  const float* src = ef + (size_t)e*32;
  ushort* dst = efh + (size_t)pos*32;              // 64B-aligned full line
  #pragma unroll
  for (int g=0; g<4; ++g){
    float4 x0 = *(const float4*)(src + g*8);
    float4 x1 = *(const float4*)(src + g*8 + 4);
    ushort8_t o;
    o[0]=f2bf(x0.x); o[1]=f2bf(x0.y); o[2]=f2bf(x0.z); o[3]=f2bf(x0.w);
    o[4]=f2bf(x1.x); o[5]=f2bf(x1.y); o[6]=f2bf(x1.z); o[7]=f2bf(x1.w);
    *(ushort8_t*)(dst + g*8) = o;
  }
}

// -------- chunk-parallel fused edge-GEMM + logit + segment-softmax accumulation --
// Wave = one 16-edge chunk (proven local optimum). r17 micro-opts: Sb gather
// chain issued FIRST (longest latency); interior runs (start AND end inside the
// chunk = node's complete segment) flush with plain stores instead of atomics.

template<int H>
__global__ void k_pool(const int* __restrict__ ssend, const int* __restrict__ srecv,
                       const ushort* __restrict__ efh,
                       const float* __restrict__ Q, const ushort* __restrict__ Sb,
                       const ushort* __restrict__ WeH, const ushort* __restrict__ WeL,
                       const float* __restrict__ a,
                       float* __restrict__ num, float* __restrict__ den){
  __shared__ float Elds[4][16*66];
  int tid = threadIdx.x;
  int chunk = blockIdx.x*4 + (tid>>6);
  uint c = tid & 63;
  float* El = Elds[tid>>6];
  int m = (int)(c & 15), quad = (int)(c >> 4);
  constexpr int CH = 64 / H;
  int p = chunk*16;

  // LONGEST-LATENCY chain first: ssend (coalesced) -> Sb row gathers (random)
  ushort sbv[16];
  #pragma unroll
  for (int t=0;t<16;++t) sbv[t] = Sb[(uint)ssend[p+t]*64u + c];

  // independent loads issue under the gather latency
  int srv[16];
  #pragma unroll
  for (int t=0;t<16;++t) srv[t] = srecv[p+t];
  bf16x8 ah = *(const bf16x8*)(efh + (size_t)(p + m)*32 + quad*8);
  float av = a[c] * 1.4426950408889634f;

  // We B-fragments (L1/L2-hot)
  bf16x8 BH[4], BL[4];
  #pragma unroll
  for (int t4=0;t4<4;++t4){
    size_t fo = ((size_t)quad*64 + t4*16 + m)*8;
    BH[t4] = *(const bf16x8*)(WeH + fo);
    BL[t4] = *(const bf16x8*)(WeL + fo);
  }

  // E tile = efh_chunk @ We (hi+lo), f32 into per-wave LDS (stride 66)
  #pragma unroll
  for (int t4=0;t4<4;++t4){
    floatx4 acc = {0.f,0.f,0.f,0.f};
    acc = __builtin_amdgcn_mfma_f32_16x16x32_bf16(ah, BL[t4], acc, 0,0,0);
    acc = __builtin_amdgcn_mfma_f32_16x16x32_bf16(ah, BH[t4], acc, 0,0,0);
    #pragma unroll
    for (int r=0;r<4;++r)
      El[(quad*4+r)*66 + t4*16 + m] = acc[r];
  }

  // consume 16 edges; per receiver-run accumulation. Runs that START inside the
  // chunk (runstart>0) and end at an interior boundary are the node's COMPLETE
  // segment -> plain store (no other wave touches it). First/last runs may span
  // chunk borders -> atomic.
  int cur = srv[0];
  float q = Q[(uint)cur*64u + c];
  float ls = 0.f, as_ = 0.f;
  int runstart = 0;
  #pragma unroll
  for (int t=0;t<16;++t){
    if (t > 0 && srv[t] != cur){                     // wave-uniform branch
      if (runstart > 0){
        num[(size_t)cur*64 + c] = as_;               // complete segment: store
        if (m == 0) den[(size_t)cur*4 + quad] = ls;
      } else {
        atomicAdd(&num[(size_t)cur*64 + c], as_);
        if (m == 0) atomicAdd(&den[(size_t)cur*4 + quad], ls);
      }
      cur = srv[t]; runstart = t;
      q = Q[(uint)cur*64u + c];
      ls = 0.f; as_ = 0.f;
    }
    float k = bf2f(sbv[t]) + El[t*66 + (int)c];
    float f = q + k;
    f = fmaxf(f, 0.2f*f);                            // leaky_relu 0.2
    float w = exp2f(lane_sum<CH>(f*av));
    ls += w;
    as_ = fmaf(w, k, as_);
  }
  atomicAdd(&num[(size_t)cur*64 + c], as_);          // may extend right: atomic
  if (m == 0) atomicAdd(&den[(size_t)cur*4 + quad], ls);
}

// -------- fused layer-1 update + layer-2 QS --------

__global__ void k_upqs(const float* __restrict__ h,
                       float* __restrict__ num, float* __restrict__ den,
                       const ushort* __restrict__ WnH, const ushort* __restrict__ WnL,
                       const float* __restrict__ bn, float* __restrict__ h1,
                       const ushort* __restrict__ WqH, const ushort* __restrict__ WqL,
                       const ushort* __restrict__ WsH, const ushort* __restrict__ WsL,
                       float* __restrict__ Q, ushort* __restrict__ Sb){
  __shared__ float Hl[4][16*66];
  int tid = threadIdx.x;
  int tile = blockIdx.x*4 + (tid>>6);
  if (tile >= NTILES) return;
  int lane = tid & 63;
  int m = lane & 15, quad = lane >> 4;
  size_t base = (size_t)tile*16;
  float* Hw = Hl[tid>>6];

  // ---- update part ----
  floatx4 acc[4];
  #pragma unroll
  for (int t=0;t<4;++t) acc[t]=(floatx4){0,0,0,0};
  #pragma unroll
  for (int ks=0; ks<4; ++ks){
    bf16x8 ah, al;
    if (ks < 2){
      split8(h + (base+m)*64 + ks*32 + quad*8, ah, al);
    } else {
      int off = (ks-2)*32 + quad*8;                  // 8-chunk lies in one head group
      float* np = num + (base+m)*64 + off;
      float dv = den[(base+m)*4 + (off>>4)];
      float inv = (dv > 0.f) ? 1.f/dv : 0.f;
      float tmp[8];
      float4 y0 = *(const float4*)np;
      float4 y1 = *(const float4*)(np+4);
      // zero num/den in place for layer 2 (this tile is ours alone)
      float4 z4 = make_float4(0.f,0.f,0.f,0.f);
      *(float4*)np = z4; *(float4*)(np+4) = z4;
      den[(base+m)*4 + (off>>4)] = 0.f;
      tmp[0]=fmaxf(y0.x*inv,0.f); tmp[1]=fmaxf(y0.y*inv,0.f);
      tmp[2]=fmaxf(y0.z*inv,0.f); tmp[3]=fmaxf(y0.w*inv,0.f);
      tmp[4]=fmaxf(y1.x*inv,0.f); tmp[5]=fmaxf(y1.y*inv,0.f);
      tmp[6]=fmaxf(y1.z*inv,0.f); tmp[7]=fmaxf(y1.w*inv,0.f);
      split8(tmp, ah, al);
    }
    int r8 = ks*4 + quad;
    #pragma unroll
    for (int t4=0;t4<4;++t4){
      size_t fo = ((size_t)r8*64 + t4*16 + m)*8;
      const bf16x8 bh = *(const bf16x8*)(WnH + fo);
      const bf16x8 bl = *(const bf16x8*)(WnL + fo);
      acc[t4] = __builtin_amdgcn_mfma_f32_16x16x32_bf16(al, bh, acc[t4],0,0,0);
      acc[t4] = __builtin_amdgcn_mfma_f32_16x16x32_bf16(ah, bl, acc[t4],0,0,0);
      acc[t4] = __builtin_amdgcn_mfma_f32_16x16x32_bf16(ah, bh, acc[t4],0,0,0);
    }
  }
  // write h1 (global, for update2) + LDS (for the qs part below)
  #pragma unroll
  for (int t4=0;t4<4;++t4){
    float b = bn[t4*16 + m];
    #pragma unroll
    for (int r=0;r<4;++r){
      float v = fmaxf(acc[t4][r] + b, 0.f);
      h1[(base + quad*4 + r)*64 + t4*16 + m] = v;
      Hw[(quad*4 + r)*66 + t4*16 + m] = v;
    }
  }

  // ---- qs part (layer 2), A-frags from LDS (same wave wrote them) ----
  floatx4 accQ[4], accS[4];
  #pragma unroll
  for (int t=0;t<4;++t){ accQ[t]=(floatx4){0,0,0,0}; accS[t]=(floatx4){0,0,0,0}; }
  #pragma unroll
  for (int ks=0; ks<2; ++ks){
    bf16x8 ah, al;
    split8(&Hw[m*66 + ks*32 + quad*8], ah, al);
    int r8 = ks*4 + quad;
    #pragma unroll
    for (int t4=0;t4<4;++t4){
      size_t fo = ((size_t)r8*64 + t4*16 + m)*8;
      const bf16x8 bh = *(const bf16x8*)(WqH + fo);
      const bf16x8 bl = *(const bf16x8*)(WqL + fo);
      const bf16x8 ch = *(const bf16x8*)(WsH + fo);
      const bf16x8 cl = *(const bf16x8*)(WsL + fo);
      accQ[t4] = __builtin_amdgcn_mfma_f32_16x16x32_bf16(al, bh, accQ[t4],0,0,0);
      accQ[t4] = __builtin_amdgcn_mfma_f32_16x16x32_bf16(ah, bl, accQ[t4],0,0,0);
      accQ[t4] = __builtin_amdgcn_mfma_f32_16x16x32_bf16(ah, bh, accQ[t4],0,0,0);
      accS[t4] = __builtin_amdgcn_mfma_f32_16x16x32_bf16(al, ch, accS[t4],0,0,0);
      accS[t4] = __builtin_amdgcn_mfma_f32_16x16x32_bf16(ah, cl, accS[t4],0,0,0);
      accS[t4] = __builtin_amdgcn_mfma_f32_16x16x32_bf16(ah, ch, accS[t4],0,0,0);
    }
  }
  #pragma unroll
  for (int t4=0;t4<4;++t4)
    #pragma unroll
    for (int r=0;r<4;++r){
      size_t row = base + quad*4 + r;
      Q[row*64 + t4*16 + m]  = accQ[t4][r];
      Sb[row*64 + t4*16 + m] = f2bf(accS[t4][r]);
    }
}

// -------- final node update via MFMA + fused readout --------

__global__ void k_update2(const float* __restrict__ h,
                          const float* __restrict__ num, const float* __restrict__ den,
                          const ushort* __restrict__ WnH, const ushort* __restrict__ WnL,
                          const float* __restrict__ bn,
                          const float* __restrict__ Wd, const float* __restrict__ bd,
                          float* __restrict__ out){
  int tid = threadIdx.x;
  int tile = blockIdx.x*4 + (tid>>6);
  if (tile >= NTILES) return;
  int lane = tid & 63;
  int m = lane & 15, quad = lane >> 4;
  size_t base = (size_t)tile*16;
  floatx4 acc[4];
  #pragma unroll
  for (int t=0;t<4;++t) acc[t]=(floatx4){0,0,0,0};
  #pragma unroll
  for (int ks=0; ks<4; ++ks){
    bf16x8 ah, al;
    if (ks < 2){
      split8(h + (base+m)*64 + ks*32 + quad*8, ah, al);
    } else {
      int off = (ks-2)*32 + quad*8;                  // 8-chunk lies in one head group
      const float* np = num + (base+m)*64 + off;
      float dv = den[(base+m)*4 + (off>>4)];
      float inv = (dv > 0.f) ? 1.f/dv : 0.f;
      float tmp[8];
      float4 y0 = *(const float4*)np;
      float4 y1 = *(const float4*)(np+4);
      tmp[0]=fmaxf(y0.x*inv,0.f); tmp[1]=fmaxf(y0.y*inv,0.f);
      tmp[2]=fmaxf(y0.z*inv,0.f); tmp[3]=fmaxf(y0.w*inv,0.f);
      tmp[4]=fmaxf(y1.x*inv,0.f); tmp[5]=fmaxf(y1.y*inv,0.f);
      tmp[6]=fmaxf(y1.z*inv,0.f); tmp[7]=fmaxf(y1.w*inv,0.f);
      split8(tmp, ah, al);
    }
    int r8 = ks*4 + quad;
    #pragma unroll
    for (int t4=0;t4<4;++t4){
      size_t fo = ((size_t)r8*64 + t4*16 + m)*8;
      const bf16x8 bh = *(const bf16x8*)(WnH + fo);
      const bf16x8 bl = *(const bf16x8*)(WnL + fo);
      acc[t4] = __builtin_amdgcn_mfma_f32_16x16x32_bf16(al, bh, acc[t4],0,0,0);
      acc[t4] = __builtin_amdgcn_mfma_f32_16x16x32_bf16(ah, bl, acc[t4],0,0,0);
      acc[t4] = __builtin_amdgcn_mfma_f32_16x16x32_bf16(ah, bh, acc[t4],0,0,0);
    }
  }
  float bv[4], wd[4];
  #pragma unroll
  for (int t4=0;t4<4;++t4){ bv[t4] = bn[t4*16+m]; wd[t4] = Wd[t4*16+m]; }
  #pragma unroll
  for (int r=0;r<4;++r){
    float v = 0.f;
    #pragma unroll
    for (int t4=0;t4<4;++t4) v += fmaxf(acc[t4][r] + bv[t4], 0.f) * wd[t4];
    #pragma unroll
    for (int off=1; off<16; off<<=1) v += __shfl_xor(v, off);  // stays in quad
    if (m == 0) out[base + quad*4 + r] = v + bd[0];
  }
}

extern "C" void kernel_launch(void* const* d_in, const int* in_sizes, int n_in,
                              void* d_out, int out_size, void* d_ws, size_t ws_size,
                              hipStream_t stream){
  const float* node_feats = (const float*)d_in[0];
  const float* edge_feats = (const float*)d_in[1];
  const int*   senders    = (const int*)d_in[2];
  const int*   receivers  = (const int*)d_in[3];
  const float* Wq1 = (const float*)d_in[4];
  const float* Ws1 = (const float*)d_in[5];
  const float* We1 = (const float*)d_in[6];
  const float* a1  = (const float*)d_in[7];
  const float* Wn1 = (const float*)d_in[8];
  const float* bn1 = (const float*)d_in[9];
  const float* Wq2 = (const float*)d_in[10];
  const float* Ws2 = (const float*)d_in[11];
  const float* We2 = (const float*)d_in[12];
  const float* a2  = (const float*)d_in[13];
  const float* Wn2 = (const float*)d_in[14];
  const float* bn2 = (const float*)d_in[15];
  const float* Wd  = (const float*)d_in[16];
  const float* bd  = (const float*)d_in[17];
  float* out = (float*)d_out;

  // workspace layout (~110 MB of the 409.6 MB ws); all blocks 64B-aligned
  char* base = (char*)d_ws;
  const size_t NF = (size_t)NNODES*64;
  int*    counts = (int*)base;  base += (size_t)NNODES*4;       //  0.2 MB
  float*  num    = (float*)base; base += NF*4;                  // 12.8 MB
  float*  den    = (float*)base; base += (size_t)NNODES*4*4;    //  0.8 MB
  float*  Q    = (float*)base;  base += NF*4;                   // 12.8 MB
  ushort* Sb   = (ushort*)base; base += NF*2;                   //  6.4 MB (bf16)
  float*  h1   = (float*)base;  base += NF*4;                   // 12.8 MB
  ushort* efh  = (ushort*)base; base += (size_t)NEDGES*32*2;    // 51.2 MB (sorted bf16 ef)
  int* ssend      = (int*)base; base += (size_t)NEDGES*4;       //  3.2 MB
  int* srecv      = (int*)base; base += (size_t)NEDGES*4;       //  3.2 MB
  int* rank       = (int*)base; base += (size_t)NEDGES*4;       //  3.2 MB
  int* offsets    = (int*)base; base += (size_t)(NNODES+1)*4;
  ushort* wsp     = (ushort*)base; base += (size_t)73728*2;     // pre-split weights
  int* bsum       = (int*)base; base += (size_t)NB_SCAN*4;

  if (ws_size < (size_t)(base - (char*)d_ws)) return;  // tripwire: out stays 0

  const ushort *Wq1H=wsp+0,     *Wq1L=wsp+4096,  *Ws1H=wsp+8192,  *Ws1L=wsp+12288;
  const ushort *Wn1H=wsp+16384, *Wn1L=wsp+24576, *Wq2H=wsp+32768, *Wq2L=wsp+36864;
  const ushort *Ws2H=wsp+40960, *Ws2L=wsp+45056, *Wn2H=wsp+49152, *Wn2L=wsp+57344;
  const ushort *We1H=wsp+65536, *We1L=wsp+67584, *We2H=wsp+69632, *We2L=wsp+71680;

  dim3 b256(256);

  // 1: zero counts only (num/den zeroed inside scatperm extension blocks)
  hipMemsetAsync(counts, 0, (size_t)NNODES*4, stream);
  // 2: fused hist+rank + weight pre-split
  k_init     <<<NB_HIST + (4608+255)/256, b256, 0, stream>>>(receivers, counts, rank,
                Wq1,Ws1,Wn1,Wq2,Ws2,Wn2,We1,We2, wsp);
  // 3-4: scan (scantop folded into scanfinal; each block redundantly scans bsum)
  k_blocksum <<<NB_SCAN, b256, 0, stream>>>(counts, bsum);
  k_scanfinal<<<NB_SCAN, b256, 0, stream>>>(counts, bsum, offsets);
  // 5: fused scatter+permute (atomic-free: offsets+rank) + srecv/ZND + layer-1 QS
  k_scatperm <<<NB_EDGE + NB_SCAN + NB_NODE, b256, 0, stream>>>(
                receivers, senders, rank, edge_feats, efh, ssend, offsets, srecv,
                num, den, node_feats, Wq1H,Wq1L, Ws1H,Ws1L, Q, Sb);

  // ---- layer 1 (H=4) ----
  k_pool<4> <<<NB_POOL, b256, 0, stream>>>(ssend, srecv, efh, Q, Sb,
                                           We1H, We1L, a1, num, den);
  // fused: update1 (writes h1, zeroes num/den) + layer-2 QS
  k_upqs <<<NB_NODE, b256, 0, stream>>>(node_feats, num, den, Wn1H, Wn1L, bn1, h1,
                                        Wq2H,Wq2L, Ws2H,Ws2L, Q, Sb);

  // ---- layer 2 (H=1) + fused readout ----
  k_pool<1> <<<NB_POOL, b256, 0, stream>>>(ssend, srecv, efh, Q, Sb,
                                           We2H, We2L, a2, num, den);
  k_update2 <<<NB_NODE, b256, 0, stream>>>(h1, num, den, Wn2H, Wn2L, bn2,
                                           Wd, bd, out);
}

// Round 18
// 393.808 us; speedup vs baseline: 1.0478x; 1.0478x over previous
//
#include <hip/hip_runtime.h>
#include <hip/hip_bf16.h>

#define NNODES 50000
#define NEDGES 800000
#define UNITS 64
#define NTILES (NNODES/16)         // 3125 exact
#define NB_SCAN ((NNODES+255)/256) // 196
#define NB_NODE ((NTILES+3)/4)     // 782
#define NB_HIST ((NEDGES+255)/256) // 3125
#define NB_EDGE (NEDGES/256)       // 3125 exact
#define NB_POOL (NEDGES/16/4)      // 12500 exact (16-edge chunks, 4 waves/block)

typedef unsigned short ushort;
typedef unsigned int uint;
typedef __attribute__((ext_vector_type(8))) short bf16x8;
typedef __attribute__((ext_vector_type(4))) float floatx4;
typedef __attribute__((ext_vector_type(8))) ushort ushort8_t;

__device__ __forceinline__ ushort f2bf(float x){
  union{float f; uint u;} v; v.f = x;
  uint r = v.u + 0x7fffu + ((v.u >> 16) & 1u);   // RNE
  return (ushort)(r >> 16);
}
__device__ __forceinline__ float bf2f(ushort h){
  union{uint u; float f;} v; v.u = ((uint)h) << 16; return v.f;
}
__device__ __forceinline__ void split8(const float* __restrict__ p, bf16x8& hi, bf16x8& lo){
  #pragma unroll
  for (int j=0;j<8;++j){
    float x = p[j];
    ushort h = f2bf(x);
    hi[j] = (short)h;
    lo[j] = (short)f2bf(x - bf2f(h));
  }
}

// DPP butterfly add (VALU pipe, no LDS): xor1, xor2, xor7, xor15 basis -> 16-lane sum
template<int CTRL>
__device__ __forceinline__ float dpp_add(float x){
  int y = __builtin_amdgcn_update_dpp(0, __float_as_int(x), CTRL, 0xF, 0xF, true);
  return x + __int_as_float(y);
}
template<int CH>
__device__ __forceinline__ float lane_sum(float p){
  p = dpp_add<0xB1>(p);    // quad_perm xor1
  p = dpp_add<0x4E>(p);    // quad_perm xor2
  p = dpp_add<0x141>(p);   // row_half_mirror = xor7
  p = dpp_add<0x140>(p);   // row_mirror = xor15
  if (CH == 64){
    p += __shfl_xor(p, 16);
    p += __shfl_xor(p, 32);
  }
  return p;
}

// -------- weight pre-split unit (MFMA B-fragment order, bf16 hi/lo) --------

__device__ __forceinline__ void packunit(const float* __restrict__ W, int r8, int col,
                                         ushort* __restrict__ H, ushort* __restrict__ L){
  bf16x8 hi, lo;
  #pragma unroll
  for (int j=0;j<8;++j){
    float x = W[(r8*8+j)*64 + col];
    ushort h = f2bf(x);
    hi[j] = (short)h;
    lo[j] = (short)f2bf(x - bf2f(h));
  }
  *(bf16x8*)(H + ((size_t)r8*64 + col)*8) = hi;
  *(bf16x8*)(L + ((size_t)r8*64 + col)*8) = lo;
}

// -------- fused: hist+rank (blocks 0..NB_HIST) + splitw (rest) --------

__global__ void k_init(const int* __restrict__ recv, int* __restrict__ counts,
                       int* __restrict__ rank,
                       const float* __restrict__ Wq1, const float* __restrict__ Ws1,
                       const float* __restrict__ Wn1, const float* __restrict__ Wq2,
                       const float* __restrict__ Ws2, const float* __restrict__ Wn2,
                       const float* __restrict__ We1, const float* __restrict__ We2,
                       ushort* __restrict__ wsp){
  if (blockIdx.x < NB_HIST){
    int e = blockIdx.x*blockDim.x + threadIdx.x;
    if (e < NEDGES) rank[e] = atomicAdd(&counts[recv[e]], 1);
    return;
  }
  int u = (blockIdx.x - NB_HIST)*blockDim.x + threadIdx.x;   // 4608 units
  if (u >= 4608) return;
  ushort* p = wsp;
  const float* W; int base;
  if      (u < 512){  W=Wq1; base=u;        p += 0;      packunit(W, base>>6, base&63, p, p+4096); return; }
  else if (u < 1024){ W=Ws1; base=u-512;    p += 8192;   packunit(W, base>>6, base&63, p, p+4096); return; }
  else if (u < 2048){ W=Wn1; base=u-1024;   p += 16384;  packunit(W, base>>6, base&63, p, p+8192); return; }
  else if (u < 2560){ W=Wq2; base=u-2048;   p += 32768;  packunit(W, base>>6, base&63, p, p+4096); return; }
  else if (u < 3072){ W=Ws2; base=u-2560;   p += 40960;  packunit(W, base>>6, base&63, p, p+4096); return; }
  else if (u < 4096){ W=Wn2; base=u-3072;   p += 49152;  packunit(W, base>>6, base&63, p, p+8192); return; }
  else if (u < 4352){ W=We1; base=u-4096;   p += 65536;  packunit(W, base>>6, base&63, p, p+2048); return; }
  else {              W=We2; base=u-4352;   p += 69632;  packunit(W, base>>6, base&63, p, p+2048); return; }
}

// ---------------- scan: blocksum + fused(top-scan + final) ----------------

__global__ void k_blocksum(const int* __restrict__ counts, int* __restrict__ bsum){
  __shared__ int red[256];
  int b = blockIdx.x, t = threadIdx.x;
  int i = b*256 + t;
  red[t] = (i < NNODES) ? counts[i] : 0;
  __syncthreads();
  for (int s=128; s>0; s>>=1){ if (t<s) red[t]+=red[t+s]; __syncthreads(); }
  if (t==0) bsum[b] = red[0];
}

// each block redundantly reduces bsum[0..b) (196 L2-hot ints) for its prefix
__global__ void k_scanfinal(const int* __restrict__ counts, const int* __restrict__ bsum,
                            int* __restrict__ offsets){
  __shared__ int red[256];
  int b = blockIdx.x, t = threadIdx.x;
  red[t] = (t < b) ? bsum[t] : 0;                 // NB_SCAN <= 256
  __syncthreads();
  for (int s=128; s>0; s>>=1){ if (t<s) red[t]+=red[t+s]; __syncthreads(); }
  int pre = red[0];                               // exclusive block prefix
  __syncthreads();
  int i = b*256 + t;
  int own = (i < NNODES) ? counts[i] : 0;
  red[t] = own;
  __syncthreads();
  for (int s=1; s<256; s<<=1){
    int u = (t>=s) ? red[t-s] : 0;
    __syncthreads();
    red[t] += u;
    __syncthreads();
  }
  if (i < NNODES) offsets[i] = pre + red[t] - own;
  if (b == 0 && t == 0) offsets[NNODES] = NEDGES;
}

// -------- node transform tile: Q = h@Wq (fp32), Sb = h@Ws (bf16) --------

__device__ __forceinline__ void qs_tile(const float* __restrict__ h,
                                        const ushort* __restrict__ WqH, const ushort* __restrict__ WqL,
                                        const ushort* __restrict__ WsH, const ushort* __restrict__ WsL,
                                        float* __restrict__ Q, ushort* __restrict__ Sb,
                                        int tile, int tid){
  int lane = tid & 63;
  int m = lane & 15, quad = lane >> 4;
  size_t base = (size_t)tile*16;
  floatx4 accQ[4], accS[4];
  #pragma unroll
  for (int t=0;t<4;++t){ accQ[t]=(floatx4){0,0,0,0}; accS[t]=(floatx4){0,0,0,0}; }
  #pragma unroll
  for (int ks=0; ks<2; ++ks){
    bf16x8 ah, al;
    split8(h + (base+m)*64 + ks*32 + quad*8, ah, al);
    int r8 = ks*4 + quad;
    #pragma unroll
    for (int t4=0;t4<4;++t4){
      size_t fo = ((size_t)r8*64 + t4*16 + m)*8;
      const bf16x8 bh = *(const bf16x8*)(WqH + fo);
      const bf16x8 bl = *(const bf16x8*)(WqL + fo);
      const bf16x8 ch = *(const bf16x8*)(WsH + fo);
      const bf16x8 cl = *(const bf16x8*)(WsL + fo);
      accQ[t4] = __builtin_amdgcn_mfma_f32_16x16x32_bf16(al, bh, accQ[t4],0,0,0);
      accQ[t4] = __builtin_amdgcn_mfma_f32_16x16x32_bf16(ah, bl, accQ[t4],0,0,0);
      accQ[t4] = __builtin_amdgcn_mfma_f32_16x16x32_bf16(ah, bh, accQ[t4],0,0,0);
      accS[t4] = __builtin_amdgcn_mfma_f32_16x16x32_bf16(al, ch, accS[t4],0,0,0);
      accS[t4] = __builtin_amdgcn_mfma_f32_16x16x32_bf16(ah, cl, accS[t4],0,0,0);
      accS[t4] = __builtin_amdgcn_mfma_f32_16x16x32_bf16(ah, ch, accS[t4],0,0,0);
    }
  }
  #pragma unroll
  for (int t4=0;t4<4;++t4)
    #pragma unroll
    for (int r=0;r<4;++r){
      size_t row = base + quad*4 + r;
      Q[row*64 + t4*16 + m]  = accQ[t4][r];
      Sb[row*64 + t4*16 + m] = f2bf(accS[t4][r]);
    }
}

// -------- fused scatter+permute + layer-1 QS: ONE dispatch, NO atomics --------
// Edge blocks at the random-access BW floor (~2.2 TB/s, r14) -- structural.

__global__ void k_scatperm(const int* __restrict__ recv, const int* __restrict__ send,
                           const int* __restrict__ rank,
                           const float* __restrict__ ef,
                           ushort* __restrict__ efh, int* __restrict__ ssend,
                           const int* __restrict__ offsets, int* __restrict__ srecv,
                           float* __restrict__ num, float* __restrict__ den,
                           const float* __restrict__ h,
                           const ushort* __restrict__ WqH, const ushort* __restrict__ WqL,
                           const ushort* __restrict__ WsH, const ushort* __restrict__ WsL,
                           float* __restrict__ Q, ushort* __restrict__ Sb){
  if (blockIdx.x >= NB_EDGE + NB_SCAN){
    int tile = (int)(blockIdx.x - NB_EDGE - NB_SCAN)*4 + (threadIdx.x>>6);
    if (tile < NTILES) qs_tile(h, WqH, WqL, WsH, WsL, Q, Sb, tile, threadIdx.x);
    return;
  }
  if (blockIdx.x >= NB_EDGE){
    int n = (blockIdx.x - NB_EDGE)*256 + threadIdx.x;
    if (n < NNODES){
      int b = offsets[n], e = offsets[n+1];
      for (int j=b; j<e; ++j) srecv[j] = n;
      floatx4 z = {0.f,0.f,0.f,0.f};
      floatx4* pn = (floatx4*)(num + (size_t)n*64);
      #pragma unroll
      for (int j=0;j<16;++j) pn[j] = z;
      *(floatx4*)(den + (size_t)n*4) = z;
    }
    return;
  }
  int e = blockIdx.x*256 + threadIdx.x;            // NEDGES = 256*3125 exact
  int r = recv[e];
  int sv = send[e];
  int pos = offsets[r] + rank[e];
  ssend[pos] = sv;
  const float* src = ef + (size_t)e*32;
  ushort* dst = efh + (size_t)pos*32;              // 64B-aligned full line
  #pragma unroll
  for (int g=0; g<4; ++g){
    float4 x0 = *(const float4*)(src + g*8);
    float4 x1 = *(const float4*)(src + g*8 + 4);
    ushort8_t o;
    o[0]=f2bf(x0.x); o[1]=f2bf(x0.y); o[2]=f2bf(x0.z); o[3]=f2bf(x0.w);
    o[4]=f2bf(x1.x); o[5]=f2bf(x1.y); o[6]=f2bf(x1.z); o[7]=f2bf(x1.w);
    *(ushort8_t*)(dst + g*8) = o;
  }
}

// -------- chunk-parallel fused edge-GEMM + logit + segment-softmax accumulation --
// Wave = one 16-edge chunk (r13/r16-proven local optimum: 32-edge (r12),
// pipelined (r15), reorder+store-flush (r17) all regressed; no-return atomics
// are already non-blocking, compiler schedule already optimal).

template<int H>
__global__ void k_pool(const int* __restrict__ ssend, const int* __restrict__ srecv,
                       const ushort* __restrict__ efh,
                       const float* __restrict__ Q, const ushort* __restrict__ Sb,
                       const ushort* __restrict__ WeH, const ushort* __restrict__ WeL,
                       const float* __restrict__ a,
                       float* __restrict__ num, float* __restrict__ den){
  __shared__ float Elds[4][16*66];
  int tid = threadIdx.x;
  int chunk = blockIdx.x*4 + (tid>>6);
  uint c = tid & 63;
  float* El = Elds[tid>>6];
  int m = (int)(c & 15), quad = (int)(c >> 4);
  constexpr int CH = 64 / H;
  int p = chunk*16;

  // A fragment: sequential coalesced load from sorted bf16 edge feats
  bf16x8 ah = *(const bf16x8*)(efh + (size_t)(p + m)*32 + quad*8);

  float av = a[c] * 1.4426950408889634f;

  // uniform edge meta (L1-broadcast loads) + Sb row gathers
  int srv[16];
  #pragma unroll
  for (int t=0;t<16;++t) srv[t] = srecv[p+t];
  ushort sbv[16];
  #pragma unroll
  for (int t=0;t<16;++t) sbv[t] = Sb[(uint)ssend[p+t]*64u + c];

  // We B-fragments (L2-hot)
  bf16x8 BH[4], BL[4];
  #pragma unroll
  for (int t4=0;t4<4;++t4){
    size_t fo = ((size_t)quad*64 + t4*16 + m)*8;
    BH[t4] = *(const bf16x8*)(WeH + fo);
    BL[t4] = *(const bf16x8*)(WeL + fo);
  }

  // E tile = efh_chunk @ We (hi+lo), f32 into per-wave LDS (stride 66)
  #pragma unroll
  for (int t4=0;t4<4;++t4){
    floatx4 acc = {0.f,0.f,0.f,0.f};
    acc = __builtin_amdgcn_mfma_f32_16x16x32_bf16(ah, BL[t4], acc, 0,0,0);
    acc = __builtin_amdgcn_mfma_f32_16x16x32_bf16(ah, BH[t4], acc, 0,0,0);
    #pragma unroll
    for (int r=0;r<4;++r)
      El[(quad*4+r)*66 + t4*16 + m] = acc[r];
  }

  // consume 16 edges; accumulate per receiver-run, flush at boundaries
  int cur = srv[0];
  float q = Q[(uint)cur*64u + c];
  float ls = 0.f, as_ = 0.f;
  #pragma unroll
  for (int t=0;t<16;++t){
    if (t > 0 && srv[t] != cur){                     // wave-uniform branch
      atomicAdd(&num[(size_t)cur*64 + c], as_);
      if (m == 0) atomicAdd(&den[(size_t)cur*4 + quad], ls);
      cur = srv[t];
      q = Q[(uint)cur*64u + c];
      ls = 0.f; as_ = 0.f;
    }
    float k = bf2f(sbv[t]) + El[t*66 + (int)c];
    float f = q + k;
    f = fmaxf(f, 0.2f*f);                            // leaky_relu 0.2
    float w = exp2f(lane_sum<CH>(f*av));
    ls += w;
    as_ = fmaf(w, k, as_);
  }
  atomicAdd(&num[(size_t)cur*64 + c], as_);
  if (m == 0) atomicAdd(&den[(size_t)cur*4 + quad], ls);
}

// -------- fused layer-1 update + layer-2 QS --------

__global__ void k_upqs(const float* __restrict__ h,
                       float* __restrict__ num, float* __restrict__ den,
                       const ushort* __restrict__ WnH, const ushort* __restrict__ WnL,
                       const float* __restrict__ bn, float* __restrict__ h1,
                       const ushort* __restrict__ WqH, const ushort* __restrict__ WqL,
                       const ushort* __restrict__ WsH, const ushort* __restrict__ WsL,
                       float* __restrict__ Q, ushort* __restrict__ Sb){
  __shared__ float Hl[4][16*66];
  int tid = threadIdx.x;
  int tile = blockIdx.x*4 + (tid>>6);
  if (tile >= NTILES) return;
  int lane = tid & 63;
  int m = lane & 15, quad = lane >> 4;
  size_t base = (size_t)tile*16;
  float* Hw = Hl[tid>>6];

  // ---- update part ----
  floatx4 acc[4];
  #pragma unroll
  for (int t=0;t<4;++t) acc[t]=(floatx4){0,0,0,0};
  #pragma unroll
  for (int ks=0; ks<4; ++ks){
    bf16x8 ah, al;
    if (ks < 2){
      split8(h + (base+m)*64 + ks*32 + quad*8, ah, al);
    } else {
      int off = (ks-2)*32 + quad*8;                  // 8-chunk lies in one head group
      float* np = num + (base+m)*64 + off;
      float dv = den[(base+m)*4 + (off>>4)];
      float inv = (dv > 0.f) ? 1.f/dv : 0.f;
      float tmp[8];
      float4 y0 = *(const float4*)np;
      float4 y1 = *(const float4*)(np+4);
      // zero num/den in place for layer 2 (this tile is ours alone)
      float4 z4 = make_float4(0.f,0.f,0.f,0.f);
      *(float4*)np = z4; *(float4*)(np+4) = z4;
      den[(base+m)*4 + (off>>4)] = 0.f;
      tmp[0]=fmaxf(y0.x*inv,0.f); tmp[1]=fmaxf(y0.y*inv,0.f);
      tmp[2]=fmaxf(y0.z*inv,0.f); tmp[3]=fmaxf(y0.w*inv,0.f);
      tmp[4]=fmaxf(y1.x*inv,0.f); tmp[5]=fmaxf(y1.y*inv,0.f);
      tmp[6]=fmaxf(y1.z*inv,0.f); tmp[7]=fmaxf(y1.w*inv,0.f);
      split8(tmp, ah, al);
    }
    int r8 = ks*4 + quad;
    #pragma unroll
    for (int t4=0;t4<4;++t4){
      size_t fo = ((size_t)r8*64 + t4*16 + m)*8;
      const bf16x8 bh = *(const bf16x8*)(WnH + fo);
      const bf16x8 bl = *(const bf16x8*)(WnL + fo);
      acc[t4] = __builtin_amdgcn_mfma_f32_16x16x32_bf16(al, bh, acc[t4],0,0,0);
      acc[t4] = __builtin_amdgcn_mfma_f32_16x16x32_bf16(ah, bl, acc[t4],0,0,0);
      acc[t4] = __builtin_amdgcn_mfma_f32_16x16x32_bf16(ah, bh, acc[t4],0,0,0);
    }
  }
  // write h1 (global, for update2) + LDS (for the qs part below)
  #pragma unroll
  for (int t4=0;t4<4;++t4){
    float b = bn[t4*16 + m];
    #pragma unroll
    for (int r=0;r<4;++r){
      float v = fmaxf(acc[t4][r] + b, 0.f);
      h1[(base + quad*4 + r)*64 + t4*16 + m] = v;
      Hw[(quad*4 + r)*66 + t4*16 + m] = v;
    }
  }

  // ---- qs part (layer 2), A-frags from LDS (same wave wrote them) ----
  floatx4 accQ[4], accS[4];
  #pragma unroll
  for (int t=0;t<4;++t){ accQ[t]=(floatx4){0,0,0,0}; accS[t]=(floatx4){0,0,0,0}; }
  #pragma unroll
  for (int ks=0; ks<2; ++ks){
    bf16x8 ah, al;
    split8(&Hw[m*66 + ks*32 + quad*8], ah, al);
    int r8 = ks*4 + quad;
    #pragma unroll
    for (int t4=0;t4<4;++t4){
      size_t fo = ((size_t)r8*64 + t4*16 + m)*8;
      const bf16x8 bh = *(const bf16x8*)(WqH + fo);
      const bf16x8 bl = *(const bf16x8*)(WqL + fo);
      const bf16x8 ch = *(const bf16x8*)(WsH + fo);
      const bf16x8 cl = *(const bf16x8*)(WsL + fo);
      accQ[t4] = __builtin_amdgcn_mfma_f32_16x16x32_bf16(al, bh, accQ[t4],0,0,0);
      accQ[t4] = __builtin_amdgcn_mfma_f32_16x16x32_bf16(ah, bl, accQ[t4],0,0,0);
      accQ[t4] = __builtin_amdgcn_mfma_f32_16x16x32_bf16(ah, bh, accQ[t4],0,0,0);
      accS[t4] = __builtin_amdgcn_mfma_f32_16x16x32_bf16(al, ch, accS[t4],0,0,0);
      accS[t4] = __builtin_amdgcn_mfma_f32_16x16x32_bf16(ah, cl, accS[t4],0,0,0);
      accS[t4] = __builtin_amdgcn_mfma_f32_16x16x32_bf16(ah, ch, accS[t4],0,0,0);
    }
  }
  #pragma unroll
  for (int t4=0;t4<4;++t4)
    #pragma unroll
    for (int r=0;r<4;++r){
      size_t row = base + quad*4 + r;
      Q[row*64 + t4*16 + m]  = accQ[t4][r];
      Sb[row*64 + t4*16 + m] = f2bf(accS[t4][r]);
    }
}

// -------- final node update via MFMA + fused readout --------

__global__ void k_update2(const float* __restrict__ h,
                          const float* __restrict__ num, const float* __restrict__ den,
                          const ushort* __restrict__ WnH, const ushort* __restrict__ WnL,
                          const float* __restrict__ bn,
                          const float* __restrict__ Wd, const float* __restrict__ bd,
                          float* __restrict__ out){
  int tid = threadIdx.x;
  int tile = blockIdx.x*4 + (tid>>6);
  if (tile >= NTILES) return;
  int lane = tid & 63;
  int m = lane & 15, quad = lane >> 4;
  size_t base = (size_t)tile*16;
  floatx4 acc[4];
  #pragma unroll
  for (int t=0;t<4;++t) acc[t]=(floatx4){0,0,0,0};
  #pragma unroll
  for (int ks=0; ks<4; ++ks){
    bf16x8 ah, al;
    if (ks < 2){
      split8(h + (base+m)*64 + ks*32 + quad*8, ah, al);
    } else {
      int off = (ks-2)*32 + quad*8;                  // 8-chunk lies in one head group
      const float* np = num + (base+m)*64 + off;
      float dv = den[(base+m)*4 + (off>>4)];
      float inv = (dv > 0.f) ? 1.f/dv : 0.f;
      float tmp[8];
      float4 y0 = *(const float4*)np;
      float4 y1 = *(const float4*)(np+4);
      tmp[0]=fmaxf(y0.x*inv,0.f); tmp[1]=fmaxf(y0.y*inv,0.f);
      tmp[2]=fmaxf(y0.z*inv,0.f); tmp[3]=fmaxf(y0.w*inv,0.f);
      tmp[4]=fmaxf(y1.x*inv,0.f); tmp[5]=fmaxf(y1.y*inv,0.f);
      tmp[6]=fmaxf(y1.z*inv,0.f); tmp[7]=fmaxf(y1.w*inv,0.f);
      split8(tmp, ah, al);
    }
    int r8 = ks*4 + quad;
    #pragma unroll
    for (int t4=0;t4<4;++t4){
      size_t fo = ((size_t)r8*64 + t4*16 + m)*8;
      const bf16x8 bh = *(const bf16x8*)(WnH + fo);
      const bf16x8 bl = *(const bf16x8*)(WnL + fo);
      acc[t4] = __builtin_amdgcn_mfma_f32_16x16x32_bf16(al, bh, acc[t4],0,0,0);
      acc[t4] = __builtin_amdgcn_mfma_f32_16x16x32_bf16(ah, bl, acc[t4],0,0,0);
      acc[t4] = __builtin_amdgcn_mfma_f32_16x16x32_bf16(ah, bh, acc[t4],0,0,0);
    }
  }
  float bv[4], wd[4];
  #pragma unroll
  for (int t4=0;t4<4;++t4){ bv[t4] = bn[t4*16+m]; wd[t4] = Wd[t4*16+m]; }
  #pragma unroll
  for (int r=0;r<4;++r){
    float v = 0.f;
    #pragma unroll
    for (int t4=0;t4<4;++t4) v += fmaxf(acc[t4][r] + bv[t4], 0.f) * wd[t4];
    #pragma unroll
    for (int off=1; off<16; off<<=1) v += __shfl_xor(v, off);  // stays in quad
    if (m == 0) out[base + quad*4 + r] = v + bd[0];
  }
}

extern "C" void kernel_launch(void* const* d_in, const int* in_sizes, int n_in,
                              void* d_out, int out_size, void* d_ws, size_t ws_size,
                              hipStream_t stream){
  const float* node_feats = (const float*)d_in[0];
  const float* edge_feats = (const float*)d_in[1];
  const int*   senders    = (const int*)d_in[2];
  const int*   receivers  = (const int*)d_in[3];
  const float* Wq1 = (const float*)d_in[4];
  const float* Ws1 = (const float*)d_in[5];
  const float* We1 = (const float*)d_in[6];
  const float* a1  = (const float*)d_in[7];
  const float* Wn1 = (const float*)d_in[8];
  const float* bn1 = (const float*)d_in[9];
  const float* Wq2 = (const float*)d_in[10];
  const float* Ws2 = (const float*)d_in[11];
  const float* We2 = (const float*)d_in[12];
  const float* a2  = (const float*)d_in[13];
  const float* Wn2 = (const float*)d_in[14];
  const float* bn2 = (const float*)d_in[15];
  const float* Wd  = (const float*)d_in[16];
  const float* bd  = (const float*)d_in[17];
  float* out = (float*)d_out;

  // workspace layout (~110 MB of the 409.6 MB ws); all blocks 64B-aligned
  char* base = (char*)d_ws;
  const size_t NF = (size_t)NNODES*64;
  int*    counts = (int*)base;  base += (size_t)NNODES*4;       //  0.2 MB
  float*  num    = (float*)base; base += NF*4;                  // 12.8 MB
  float*  den    = (float*)base; base += (size_t)NNODES*4*4;    //  0.8 MB
  float*  Q    = (float*)base;  base += NF*4;                   // 12.8 MB
  ushort* Sb   = (ushort*)base; base += NF*2;                   //  6.4 MB (bf16)
  float*  h1   = (float*)base;  base += NF*4;                   // 12.8 MB
  ushort* efh  = (ushort*)base; base += (size_t)NEDGES*32*2;    // 51.2 MB (sorted bf16 ef)
  int* ssend      = (int*)base; base += (size_t)NEDGES*4;       //  3.2 MB
  int* srecv      = (int*)base; base += (size_t)NEDGES*4;       //  3.2 MB
  int* rank       = (int*)base; base += (size_t)NEDGES*4;       //  3.2 MB
  int* offsets    = (int*)base; base += (size_t)(NNODES+1)*4;
  ushort* wsp     = (ushort*)base; base += (size_t)73728*2;     // pre-split weights
  int* bsum       = (int*)base; base += (size_t)NB_SCAN*4;

  if (ws_size < (size_t)(base - (char*)d_ws)) return;  // tripwire: out stays 0

  const ushort *Wq1H=wsp+0,     *Wq1L=wsp+4096,  *Ws1H=wsp+8192,  *Ws1L=wsp+12288;
  const ushort *Wn1H=wsp+16384, *Wn1L=wsp+24576, *Wq2H=wsp+32768, *Wq2L=wsp+36864;
  const ushort *Ws2H=wsp+40960, *Ws2L=wsp+45056, *Wn2H=wsp+49152, *Wn2L=wsp+57344;
  const ushort *We1H=wsp+65536, *We1L=wsp+67584, *We2H=wsp+69632, *We2L=wsp+71680;

  dim3 b256(256);

  // 1: zero counts only (num/den zeroed inside scatperm extension blocks)
  hipMemsetAsync(counts, 0, (size_t)NNODES*4, stream);
  // 2: fused hist+rank + weight pre-split
  k_init     <<<NB_HIST + (4608+255)/256, b256, 0, stream>>>(receivers, counts, rank,
                Wq1,Ws1,Wn1,Wq2,Ws2,Wn2,We1,We2, wsp);
  // 3-4: scan (scantop folded into scanfinal; each block redundantly scans bsum)
  k_blocksum <<<NB_SCAN, b256, 0, stream>>>(counts, bsum);
  k_scanfinal<<<NB_SCAN, b256, 0, stream>>>(counts, bsum, offsets);
  // 5: fused scatter+permute (atomic-free: offsets+rank) + srecv/ZND + layer-1 QS
  k_scatperm <<<NB_EDGE + NB_SCAN + NB_NODE, b256, 0, stream>>>(
                receivers, senders, rank, edge_feats, efh, ssend, offsets, srecv,
                num, den, node_feats, Wq1H,Wq1L, Ws1H,Ws1L, Q, Sb);

  // ---- layer 1 (H=4) ----
  k_pool<4> <<<NB_POOL, b256, 0, stream>>>(ssend, srecv, efh, Q, Sb,
                                           We1H, We1L, a1, num, den);
  // fused: update1 (writes h1, zeroes num/den) + layer-2 QS
  k_upqs <<<NB_NODE, b256, 0, stream>>>(node_feats, num, den, Wn1H, Wn1L, bn1, h1,
                                        Wq2H,Wq2L, Ws2H,Ws2L, Q, Sb);

  // ---- layer 2 (H=1) + fused readout ----
  k_pool<1> <<<NB_POOL, b256, 0, stream>>>(ssend, srecv, efh, Q, Sb,
                                           We2H, We2L, a2, num, den);
  k_update2 <<<NB_NODE, b256, 0, stream>>>(h1, num, den, Wn2H, Wn2L, bn2,
                                           Wd, bd, out);
}